// Round 18
// baseline (37.127 us; speedup 1.0000x reference)
//
#include <hip/hip_runtime.h>
#include <math.h>

// Problem constants
#define B_SZ   8192
#define D_IN   512
#define M0_N   128
#define M1_N   128
#define K_TOP  8
#define H_DIM  128
#define ROWS   16          // batch rows per compute block (4 rows per wave)
#define XP     520         // LDS x-tile row pitch (floats)

// ws layout (ints):
//   [0..1]       idx_out  (top-2 modules of emb_out)
//   [64..1087]   pre1[col*8+r] : top-8 of emb1[task][:,col], all 128 cols
//   [2048..3071] pre0[col*8+r] : top-8 of emb0[task][:,col], all 128 cols

// ---------------------------------------------------------------------------
// Wave-parallel iterative top-k, jax.lax.top_k semantics (descending value,
// ties -> lowest index). NCH*64 candidates; lane 0 writes out_idx.
template<int NCH>
__device__ __forceinline__ void wave_topk(const float* __restrict__ base,
                                          int stride, int k, int* out_idx,
                                          int lane) {
  float v[NCH];
#pragma unroll
  for (int t = 0; t < NCH; ++t) v[t] = base[(t * 64 + lane) * stride];
  for (int r = 0; r < k; ++r) {
    float bv = -INFINITY;
    int bd = 0x7fffffff;
#pragma unroll
    for (int t = 0; t < NCH; ++t) {
      if (v[t] > bv) { bv = v[t]; bd = t * 64 + lane; }
    }
#pragma unroll
    for (int m = 1; m < 64; m <<= 1) {
      float ov = __shfl_xor(bv, m, 64);
      int   od = __shfl_xor(bd, m, 64);
      if (ov > bv || (ov == bv && od < bd)) { bv = ov; bd = od; }
    }
    if (lane == 0) out_idx[r] = bd;
    if ((bd & 63) == lane) {
      const int tw = bd >> 6;
#pragma unroll
      for (int tt = 0; tt < NCH; ++tt)
        if (tt == tw) v[tt] = -INFINITY;
    }
  }
}

// ---------------------------------------------------------------------------
// Speculative routing: top-8 for ALL columns of emb1 and emb0, one column per
// wave (256 waves chip-wide). Block(0,0) wave 0 also does emb_out top-2.
__global__ __launch_bounds__(256)
void route_pre(const int* __restrict__ task_id_p,
               const float* __restrict__ emb0,
               const float* __restrict__ emb1,
               const float* __restrict__ emb_out,
               int* __restrict__ ws) {
  const int task = task_id_p[0];
  const int lane = threadIdx.x & 63;
  const int wid  = threadIdx.x >> 6;
  const int col  = blockIdx.x * 4 + wid;
  if (blockIdx.y == 0) {
    wave_topk<2>(emb1 + (size_t)task * M0_N * M1_N + col, M1_N, K_TOP,
                 ws + 64 + col * 8, lane);
    if (blockIdx.x == 0 && wid == 0)
      wave_topk<2>(emb_out + task * M1_N, 1, 2, ws, lane);
  } else {
    wave_topk<8>(emb0 + (size_t)task * D_IN * M0_N + col, M0_N, K_TOP,
                 ws + 2048 + col * 8, lane);
  }
}

// ---------------------------------------------------------------------------
// 16-lane sum reduce entirely on the VALU pipe via DPP (no DS ops).
__device__ __forceinline__ float dpp_add16(float p) {
  int t;
  t = __builtin_amdgcn_update_dpp(0, __float_as_int(p), 0xB1, 0xF, 0xF, true);
  p += __int_as_float(t);
  t = __builtin_amdgcn_update_dpp(0, __float_as_int(p), 0x4E, 0xF, 0xF, true);
  p += __int_as_float(t);
  t = __builtin_amdgcn_update_dpp(0, __float_as_int(p), 0x124, 0xF, 0xF, true);
  p += __int_as_float(t);
  t = __builtin_amdgcn_update_dpp(0, __float_as_int(p), 0x128, 0xF, 0xF, true);
  p += __int_as_float(t);
  return p;
}

// Per-thread 8-hidden-unit MLP slice + DPP reduce. Lane (g=lane&15, rq).
__device__ __forceinline__ float slice8(const float4* w1a, const float4* w1b,
                                        const float4& b1a, const float4& b1b,
                                        const float4& w2a, const float4& w2b,
                                        const float* xv) {
  float4 h0 = b1a, h1 = b1b;
#pragma unroll
  for (int k = 0; k < 8; ++k) {
    h0.x = fmaf(xv[k], w1a[k].x, h0.x);
    h0.y = fmaf(xv[k], w1a[k].y, h0.y);
    h0.z = fmaf(xv[k], w1a[k].z, h0.z);
    h0.w = fmaf(xv[k], w1a[k].w, h0.w);
    h1.x = fmaf(xv[k], w1b[k].x, h1.x);
    h1.y = fmaf(xv[k], w1b[k].y, h1.y);
    h1.z = fmaf(xv[k], w1b[k].z, h1.z);
    h1.w = fmaf(xv[k], w1b[k].w, h1.w);
  }
  float pa = 0.f, pb = 0.f;
  pa = fmaf(fmaxf(h0.x, 0.f), w2a.x, pa);
  pa = fmaf(fmaxf(h0.y, 0.f), w2a.y, pa);
  pa = fmaf(fmaxf(h0.z, 0.f), w2a.z, pa);
  pa = fmaf(fmaxf(h0.w, 0.f), w2a.w, pa);
  pb = fmaf(fmaxf(h1.x, 0.f), w2b.x, pb);
  pb = fmaf(fmaxf(h1.y, 0.f), w2b.y, pb);
  pb = fmaf(fmaxf(h1.z, 0.f), w2b.z, pb);
  pb = fmaf(fmaxf(h1.w, 0.f), w2b.w, pb);
  return dpp_add16(pa + pb);
}

// ---------------------------------------------------------------------------
// Barrier-free fused compute: ZERO __syncthreads. Each wave owns 4 rows:
// DMAs only its own 8 chunks, resolves routing itself via uniform loads
// (all lanes same address = 1 transaction, overlaps the DMA), waits on its
// OWN vmcnt(0), computes layer0 into registers res[16] (no LDS tile), then
// layer1 + sigmoid. Waves never couple -> latency of one wave's loads hides
// under other waves' compute even at 2 blocks/CU.
__global__ __launch_bounds__(256, 2)
void fused_compute(const float* __restrict__ x,
                   const float* __restrict__ W1_0, const float* __restrict__ b1_0,
                   const float* __restrict__ W2_0, const float* __restrict__ b2_0,
                   const float* __restrict__ W1_1, const float* __restrict__ b1_1,
                   const float* __restrict__ W2_1, const float* __restrict__ b2_1,
                   const int* __restrict__ ws, float* __restrict__ out) {
  __shared__ __align__(16) float xt[ROWS * XP];   // 33.3 KB x-tile

  const int tid  = threadIdx.x;
  const int wid  = tid >> 6;
  const int lane = tid & 63;
  const int rowbase = blockIdx.x * ROWS;
  const int r0 = wid * 4;               // this wave's first local row

  // ---- DMA this wave's 4 rows (8 chunks) straight into LDS ----
#pragma unroll
  for (int i = 0; i < 8; ++i) {
    const int row  = r0 + (i >> 1);
    const int half = i & 1;
    const float* gsrc = x + (size_t)(rowbase + row) * D_IN + half * 256 +
                        lane * 4;
    float* ldst = xt + row * XP + half * 256;   // wave-uniform base
    __builtin_amdgcn_global_load_lds(
        (const __attribute__((address_space(1))) void*)gsrc,
        (__attribute__((address_space(3))) void*)ldst, 16, 0, 0);
  }

  // ---- per-wave routing resolution (uniform loads; overlaps the DMA) ----
  int m1j[2];
  m1j[0] = ws[0];
  m1j[1] = ws[1];
  int m0s[16];
#pragma unroll
  for (int s = 0; s < 16; ++s)
    m0s[s] = ws[64 + m1j[s >> 3] * 8 + (s & 7)];

  // ---- wait for THIS wave's DMA (not the block's) ----
  asm volatile("s_waitcnt vmcnt(0)" ::: "memory");
  __builtin_amdgcn_sched_barrier(0);

  const int g  = lane & 15;             // h-group: units 8g..8g+7
  const int rq = lane >> 4;             // row within the wave's 4
  const float* xrow = xt + (r0 + rq) * XP;

  // ---- layer 0: all 16 slots, results in registers ----
  float res[16];
#pragma unroll
  for (int s = 0; s < 16; ++s) {
    const int m0 = m0s[s];
    const int* cp = ws + 2048 + m0 * 8;
    int cols[8];
#pragma unroll
    for (int k = 0; k < 8; ++k) cols[k] = cp[k];

    const float4* w1p = (const float4*)(W1_0 + (size_t)m0 * (K_TOP * H_DIM));
    float4 w1a[8], w1b[8];
#pragma unroll
    for (int k = 0; k < 8; ++k) {
      w1a[k] = w1p[k * 32 + 2 * g];
      w1b[k] = w1p[k * 32 + 2 * g + 1];
    }
    const float4 b1a = ((const float4*)(b1_0 + m0 * H_DIM))[2 * g];
    const float4 b1b = ((const float4*)(b1_0 + m0 * H_DIM))[2 * g + 1];
    const float4 w2a = ((const float4*)(W2_0 + m0 * H_DIM))[2 * g];
    const float4 w2b = ((const float4*)(W2_0 + m0 * H_DIM))[2 * g + 1];
    const float  b2v = b2_0[m0];

    float xv[8];
#pragma unroll
    for (int k = 0; k < 8; ++k) xv[k] = xrow[cols[k]];

    res[s] = slice8(w1a, w1b, b1a, b1b, w2a, w2b, xv) + b2v;
  }

  // ---- layer 1 (2 modules) + sigmoid, straight from registers ----
#pragma unroll
  for (int j = 0; j < 2; ++j) {
    const int m1 = m1j[j];
    const float4* w1p = (const float4*)(W1_1 + (size_t)m1 * (K_TOP * H_DIM));
    float4 w1a[8], w1b[8];
#pragma unroll
    for (int k = 0; k < 8; ++k) {
      w1a[k] = w1p[k * 32 + 2 * g];
      w1b[k] = w1p[k * 32 + 2 * g + 1];
    }
    const float4 b1a = ((const float4*)(b1_1 + m1 * H_DIM))[2 * g];
    const float4 b1b = ((const float4*)(b1_1 + m1 * H_DIM))[2 * g + 1];
    const float4 w2a = ((const float4*)(W2_1 + m1 * H_DIM))[2 * g];
    const float4 w2b = ((const float4*)(W2_1 + m1 * H_DIM))[2 * g + 1];
    const float  b2v = b2_1[m1];

    float xv[8];
#pragma unroll
    for (int k = 0; k < 8; ++k) xv[k] = res[j * 8 + k];

    const float p = slice8(w1a, w1b, b1a, b1b, w2a, w2b, xv);
    if (g == 0) {
      const float v = p + b2v;
      out[(size_t)(rowbase + r0 + rq) * 2 + j] = 1.f / (1.f + __expf(-v));
    }
  }
}

// ---------------------------------------------------------------------------
extern "C" void kernel_launch(void* const* d_in, const int* in_sizes, int n_in,
                              void* d_out, int out_size, void* d_ws, size_t ws_size,
                              hipStream_t stream) {
  const float* x       = (const float*)d_in[0];
  const int*   task_id = (const int*)  d_in[1];
  const float* emb0    = (const float*)d_in[2];
  const float* emb1    = (const float*)d_in[3];
  const float* emb_out = (const float*)d_in[4];
  const float* W1_0    = (const float*)d_in[5];
  const float* b1_0    = (const float*)d_in[6];
  const float* W2_0    = (const float*)d_in[7];
  const float* b2_0    = (const float*)d_in[8];
  const float* W1_1    = (const float*)d_in[9];
  const float* b1_1    = (const float*)d_in[10];
  const float* W2_1    = (const float*)d_in[11];
  const float* b2_1    = (const float*)d_in[12];

  int* ws = (int*)d_ws;

  route_pre<<<dim3(32, 2), 256, 0, stream>>>(task_id, emb0, emb1, emb_out, ws);
  fused_compute<<<B_SZ / ROWS, 256, 0, stream>>>(x, W1_0, b1_0, W2_0, b2_0,
                                                 W1_1, b1_1, W2_1, b2_1,
                                                 ws, (float*)d_out);
}

// Round 19
// 31.014 us; speedup vs baseline: 1.1971x; 1.1971x over previous
//
#include <hip/hip_runtime.h>
#include <math.h>

// Problem constants
#define B_SZ   8192
#define D_IN   512
#define M0_N   128
#define M1_N   128
#define K_TOP  8
#define H_DIM  128
#define ROWS   16          // batch rows per compute block
#define XP     520         // LDS x-tile row pitch (floats)

// ws layout (ints):
//   [0..1]       idx_out  (top-2 modules of emb_out)
//   [64..1087]   pre1[col*8+r] : top-8 of emb1[task][:,col], all 128 cols
//   [2048..3071] pre0[col*8+r] : top-8 of emb0[task][:,col], all 128 cols

// ---------------------------------------------------------------------------
// Wave-parallel iterative top-k, jax.lax.top_k semantics (descending value,
// ties -> lowest index). NCH*64 candidates; lane 0 writes out_idx.
template<int NCH>
__device__ __forceinline__ void wave_topk(const float* __restrict__ base,
                                          int stride, int k, int* out_idx,
                                          int lane) {
  float v[NCH];
#pragma unroll
  for (int t = 0; t < NCH; ++t) v[t] = base[(t * 64 + lane) * stride];
  for (int r = 0; r < k; ++r) {
    float bv = -INFINITY;
    int bd = 0x7fffffff;
#pragma unroll
    for (int t = 0; t < NCH; ++t) {
      if (v[t] > bv) { bv = v[t]; bd = t * 64 + lane; }
    }
#pragma unroll
    for (int m = 1; m < 64; m <<= 1) {
      float ov = __shfl_xor(bv, m, 64);
      int   od = __shfl_xor(bd, m, 64);
      if (ov > bv || (ov == bv && od < bd)) { bv = ov; bd = od; }
    }
    if (lane == 0) out_idx[r] = bd;
    if ((bd & 63) == lane) {
      const int tw = bd >> 6;
#pragma unroll
      for (int tt = 0; tt < NCH; ++tt)
        if (tt == tw) v[tt] = -INFINITY;
    }
  }
}

// ---------------------------------------------------------------------------
// Speculative routing: top-8 for ALL columns of emb1 and emb0, one column per
// wave (256 waves chip-wide). Block(0,0) wave 0 also does emb_out top-2.
__global__ __launch_bounds__(256)
void route_pre(const int* __restrict__ task_id_p,
               const float* __restrict__ emb0,
               const float* __restrict__ emb1,
               const float* __restrict__ emb_out,
               int* __restrict__ ws) {
  const int task = task_id_p[0];
  const int lane = threadIdx.x & 63;
  const int wid  = threadIdx.x >> 6;
  const int col  = blockIdx.x * 4 + wid;
  if (blockIdx.y == 0) {
    wave_topk<2>(emb1 + (size_t)task * M0_N * M1_N + col, M1_N, K_TOP,
                 ws + 64 + col * 8, lane);
    if (blockIdx.x == 0 && wid == 0)
      wave_topk<2>(emb_out + task * M1_N, 1, 2, ws, lane);
  } else {
    wave_topk<8>(emb0 + (size_t)task * D_IN * M0_N + col, M0_N, K_TOP,
                 ws + 2048 + col * 8, lane);
  }
}

// ---------------------------------------------------------------------------
// 16-lane sum reduce entirely on the VALU pipe via DPP (no DS ops).
__device__ __forceinline__ float dpp_add16(float p) {
  int t;
  t = __builtin_amdgcn_update_dpp(0, __float_as_int(p), 0xB1, 0xF, 0xF, true);
  p += __int_as_float(t);
  t = __builtin_amdgcn_update_dpp(0, __float_as_int(p), 0x4E, 0xF, 0xF, true);
  p += __int_as_float(t);
  t = __builtin_amdgcn_update_dpp(0, __float_as_int(p), 0x124, 0xF, 0xF, true);
  p += __int_as_float(t);
  t = __builtin_amdgcn_update_dpp(0, __float_as_int(p), 0x128, 0xF, 0xF, true);
  p += __int_as_float(t);
  return p;
}

// Per-thread 8-hidden-unit MLP slice + DPP reduce. Lane (g=lane&15, rq).
__device__ __forceinline__ float slice8(const float4* w1a, const float4* w1b,
                                        const float4& b1a, const float4& b1b,
                                        const float4& w2a, const float4& w2b,
                                        const float* xv) {
  float4 h0 = b1a, h1 = b1b;
#pragma unroll
  for (int k = 0; k < 8; ++k) {
    h0.x = fmaf(xv[k], w1a[k].x, h0.x);
    h0.y = fmaf(xv[k], w1a[k].y, h0.y);
    h0.z = fmaf(xv[k], w1a[k].z, h0.z);
    h0.w = fmaf(xv[k], w1a[k].w, h0.w);
    h1.x = fmaf(xv[k], w1b[k].x, h1.x);
    h1.y = fmaf(xv[k], w1b[k].y, h1.y);
    h1.z = fmaf(xv[k], w1b[k].z, h1.z);
    h1.w = fmaf(xv[k], w1b[k].w, h1.w);
  }
  float pa = 0.f, pb = 0.f;
  pa = fmaf(fmaxf(h0.x, 0.f), w2a.x, pa);
  pa = fmaf(fmaxf(h0.y, 0.f), w2a.y, pa);
  pa = fmaf(fmaxf(h0.z, 0.f), w2a.z, pa);
  pa = fmaf(fmaxf(h0.w, 0.f), w2a.w, pa);
  pb = fmaf(fmaxf(h1.x, 0.f), w2b.x, pb);
  pb = fmaf(fmaxf(h1.y, 0.f), w2b.y, pb);
  pb = fmaf(fmaxf(h1.z, 0.f), w2b.z, pb);
  pb = fmaf(fmaxf(h1.w, 0.f), w2b.w, pb);
  return dpp_add16(pa + pb);
}

// ---------------------------------------------------------------------------
// Fused compute (identical to R16 champion): x staged via global_load_lds
// DMA, per-block routing resolution overlapped with the DMA drain, layer0
// wave-specialized (wave w -> slots 4w..4w+3), DPP reduce, layer1 + sigmoid.
__global__ __launch_bounds__(256, 2)
void fused_compute(const float* __restrict__ x,
                   const float* __restrict__ W1_0, const float* __restrict__ b1_0,
                   const float* __restrict__ W2_0, const float* __restrict__ b2_0,
                   const float* __restrict__ W1_1, const float* __restrict__ b1_1,
                   const float* __restrict__ W2_1, const float* __restrict__ b2_1,
                   const int* __restrict__ ws, float* __restrict__ out) {
  __shared__ __align__(16) float xt[ROWS * XP];   // 33.3 KB x-tile
  __shared__ int   s_m1[2];
  __shared__ int   s_m0[16];
  __shared__ int   s_cols[128];
  __shared__ float tile[16 * 18];                 // layer-0 outputs [slot][row]

  const int tid  = threadIdx.x;
  const int wid  = tid >> 6;
  const int lane = tid & 63;
  const int rowbase = blockIdx.x * ROWS;

  // ---- stage x-tile via direct HBM->LDS DMA (no VGPRs, no spill) ----
#pragma unroll
  for (int i = 0; i < 8; ++i) {
    const int chunk = wid * 8 + i;      // wave-uniform, 0..31
    const int row   = chunk >> 1;       // 2 chunks per 512-float row
    const int half  = chunk & 1;
    const float* gsrc = x + (size_t)(rowbase + row) * D_IN + half * 256 +
                        lane * 4;
    float* ldst = xt + row * XP + half * 256;   // wave-uniform base
    __builtin_amdgcn_global_load_lds(
        (const __attribute__((address_space(1))) void*)gsrc,
        (__attribute__((address_space(3))) void*)ldst, 16, 0, 0);
  }

  // ---- routing resolution (L2 chain, overlaps the DMA drain) ----
  if (tid < 128) {
    const int slot = tid >> 3, k = tid & 7;
    const int m1 = ws[slot >> 3];
    const int m0 = ws[64 + m1 * 8 + (slot & 7)];
    if (k == 0) s_m0[slot] = m0;
    s_cols[tid] = ws[2048 + m0 * 8 + k];
    if (tid < 2) s_m1[tid] = ws[tid];
  }
  __syncthreads();                      // drains vmcnt -> DMA + LDS visible

  const int g  = lane & 15;             // h-group: units 8g..8g+7
  const int rq = lane >> 4;             // row-in-group 0..3

  // ---- layer 0: wave w -> slots 4w..4w+3; 4 iters x 4 rows = 16 rows ----
#pragma unroll
  for (int si = 0; si < 4; ++si) {
    const int s  = wid * 4 + si;
    const int m0 = s_m0[s];
    const float4* w1p = (const float4*)(W1_0 + (size_t)m0 * (K_TOP * H_DIM));
    float4 w1a[8], w1b[8];
#pragma unroll
    for (int k = 0; k < 8; ++k) {
      w1a[k] = w1p[k * 32 + 2 * g];
      w1b[k] = w1p[k * 32 + 2 * g + 1];
    }
    const float4 b1a = ((const float4*)(b1_0 + m0 * H_DIM))[2 * g];
    const float4 b1b = ((const float4*)(b1_0 + m0 * H_DIM))[2 * g + 1];
    const float4 w2a = ((const float4*)(W2_0 + m0 * H_DIM))[2 * g];
    const float4 w2b = ((const float4*)(W2_0 + m0 * H_DIM))[2 * g + 1];
    const float  b2v = b2_0[m0];
    int cols[8];
#pragma unroll
    for (int k = 0; k < 8; ++k) cols[k] = s_cols[s * 8 + k];

#pragma unroll
    for (int it = 0; it < 4; ++it) {
      const int r = it * 4 + rq;
      const float* xrow = xt + r * XP;
      float xv[8];
#pragma unroll
      for (int k = 0; k < 8; ++k) xv[k] = xrow[cols[k]];
      const float p = slice8(w1a, w1b, b1a, b1b, w2a, w2b, xv);
      if (g == 0) tile[s * 18 + r] = p + b2v;
    }
  }
  __syncthreads();

  // ---- layer 1: wave w -> module j=w&1, row-half w>>1; + sigmoid ----
  {
    const int j  = wid & 1;
    const int rh = wid >> 1;
    const int m1 = s_m1[j];
    const float4* w1p = (const float4*)(W1_1 + (size_t)m1 * (K_TOP * H_DIM));
    float4 w1a[8], w1b[8];
#pragma unroll
    for (int k = 0; k < 8; ++k) {
      w1a[k] = w1p[k * 32 + 2 * g];
      w1b[k] = w1p[k * 32 + 2 * g + 1];
    }
    const float4 b1a = ((const float4*)(b1_1 + m1 * H_DIM))[2 * g];
    const float4 b1b = ((const float4*)(b1_1 + m1 * H_DIM))[2 * g + 1];
    const float4 w2a = ((const float4*)(W2_1 + m1 * H_DIM))[2 * g];
    const float4 w2b = ((const float4*)(W2_1 + m1 * H_DIM))[2 * g + 1];
    const float  b2v = b2_1[m1];

#pragma unroll
    for (int it = 0; it < 2; ++it) {
      const int r = rh * 8 + it * 4 + rq;
      float xv[8];
#pragma unroll
      for (int k = 0; k < 8; ++k) xv[k] = tile[(j * 8 + k) * 18 + r];
      const float p = slice8(w1a, w1b, b1a, b1b, w2a, w2b, xv);
      if (g == 0) {
        const float v = p + b2v;
        out[(size_t)(rowbase + r) * 2 + j] = 1.f / (1.f + __expf(-v));
      }
    }
  }
}

// ---------------------------------------------------------------------------
extern "C" void kernel_launch(void* const* d_in, const int* in_sizes, int n_in,
                              void* d_out, int out_size, void* d_ws, size_t ws_size,
                              hipStream_t stream) {
  const float* x       = (const float*)d_in[0];
  const int*   task_id = (const int*)  d_in[1];
  const float* emb0    = (const float*)d_in[2];
  const float* emb1    = (const float*)d_in[3];
  const float* emb_out = (const float*)d_in[4];
  const float* W1_0    = (const float*)d_in[5];
  const float* b1_0    = (const float*)d_in[6];
  const float* W2_0    = (const float*)d_in[7];
  const float* b2_0    = (const float*)d_in[8];
  const float* W1_1    = (const float*)d_in[9];
  const float* b1_1    = (const float*)d_in[10];
  const float* W2_1    = (const float*)d_in[11];
  const float* b2_1    = (const float*)d_in[12];

  int* ws = (int*)d_ws;

  route_pre<<<dim3(32, 2), 256, 0, stream>>>(task_id, emb0, emb1, emb_out, ws);
  // Measurement launch: identical work, identical ws contents. dur_us delta
  // vs round 16 (23.9) isolates route_pre + one inter-dispatch gap.
  route_pre<<<dim3(32, 2), 256, 0, stream>>>(task_id, emb0, emb1, emb_out, ws);
  fused_compute<<<B_SZ / ROWS, 256, 0, stream>>>(x, W1_0, b1_0, W2_0, b2_0,
                                                 W1_1, b1_1, W2_1, b2_1,
                                                 ws, (float*)d_out);
}

// Round 20
// 23.779 us; speedup vs baseline: 1.5614x; 1.3043x over previous
//
#include <hip/hip_runtime.h>
#include <math.h>

// Problem constants
#define B_SZ   8192
#define D_IN   512
#define M0_N   128
#define M1_N   128
#define K_TOP  8
#define H_DIM  128
#define ROWS   16          // batch rows per compute block
#define XP     520         // LDS x-tile row pitch (floats)

// ws layout (ints):
//   [0..1]       idx_out  (top-2 modules of emb_out)
//   [64..1087]   pre1[col*8+r] : top-8 of emb1[task][:,col], all 128 cols
//   [2048..3071] pre0[col*8+r] : top-8 of emb0[task][:,col], all 128 cols

// ---------------------------------------------------------------------------
// Wave-parallel iterative top-k, jax.lax.top_k semantics (descending value,
// ties -> lowest index). NCH*64 candidates; lane 0 writes out_idx.
template<int NCH>
__device__ __forceinline__ void wave_topk(const float* __restrict__ base,
                                          int stride, int k, int* out_idx,
                                          int lane) {
  float v[NCH];
#pragma unroll
  for (int t = 0; t < NCH; ++t) v[t] = base[(t * 64 + lane) * stride];
  for (int r = 0; r < k; ++r) {
    float bv = -INFINITY;
    int bd = 0x7fffffff;
#pragma unroll
    for (int t = 0; t < NCH; ++t) {
      if (v[t] > bv) { bv = v[t]; bd = t * 64 + lane; }
    }
#pragma unroll
    for (int m = 1; m < 64; m <<= 1) {
      float ov = __shfl_xor(bv, m, 64);
      int   od = __shfl_xor(bd, m, 64);
      if (ov > bv || (ov == bv && od < bd)) { bv = ov; bd = od; }
    }
    if (lane == 0) out_idx[r] = bd;
    if ((bd & 63) == lane) {
      const int tw = bd >> 6;
#pragma unroll
      for (int tt = 0; tt < NCH; ++tt)
        if (tt == tw) v[tt] = -INFINITY;
    }
  }
}

// ---------------------------------------------------------------------------
// Speculative routing: top-8 for ALL columns of emb1 and emb0, one column per
// wave (256 waves chip-wide). Block(0,0) wave 0 also does emb_out top-2.
__global__ __launch_bounds__(256)
void route_pre(const int* __restrict__ task_id_p,
               const float* __restrict__ emb0,
               const float* __restrict__ emb1,
               const float* __restrict__ emb_out,
               int* __restrict__ ws) {
  const int task = task_id_p[0];
  const int lane = threadIdx.x & 63;
  const int wid  = threadIdx.x >> 6;
  const int col  = blockIdx.x * 4 + wid;
  if (blockIdx.y == 0) {
    wave_topk<2>(emb1 + (size_t)task * M0_N * M1_N + col, M1_N, K_TOP,
                 ws + 64 + col * 8, lane);
    if (blockIdx.x == 0 && wid == 0)
      wave_topk<2>(emb_out + task * M1_N, 1, 2, ws, lane);
  } else {
    wave_topk<8>(emb0 + (size_t)task * D_IN * M0_N + col, M0_N, K_TOP,
                 ws + 2048 + col * 8, lane);
  }
}

// ---------------------------------------------------------------------------
// 16-lane sum reduce entirely on the VALU pipe via DPP (no DS ops).
__device__ __forceinline__ float dpp_add16(float p) {
  int t;
  t = __builtin_amdgcn_update_dpp(0, __float_as_int(p), 0xB1, 0xF, 0xF, true);
  p += __int_as_float(t);
  t = __builtin_amdgcn_update_dpp(0, __float_as_int(p), 0x4E, 0xF, 0xF, true);
  p += __int_as_float(t);
  t = __builtin_amdgcn_update_dpp(0, __float_as_int(p), 0x124, 0xF, 0xF, true);
  p += __int_as_float(t);
  t = __builtin_amdgcn_update_dpp(0, __float_as_int(p), 0x128, 0xF, 0xF, true);
  p += __int_as_float(t);
  return p;
}

// Per-thread 8-hidden-unit MLP slice + DPP reduce. Lane (g=lane&15, rq).
__device__ __forceinline__ float slice8(const float4* w1a, const float4* w1b,
                                        const float4& b1a, const float4& b1b,
                                        const float4& w2a, const float4& w2b,
                                        const float* xv) {
  float4 h0 = b1a, h1 = b1b;
#pragma unroll
  for (int k = 0; k < 8; ++k) {
    h0.x = fmaf(xv[k], w1a[k].x, h0.x);
    h0.y = fmaf(xv[k], w1a[k].y, h0.y);
    h0.z = fmaf(xv[k], w1a[k].z, h0.z);
    h0.w = fmaf(xv[k], w1a[k].w, h0.w);
    h1.x = fmaf(xv[k], w1b[k].x, h1.x);
    h1.y = fmaf(xv[k], w1b[k].y, h1.y);
    h1.z = fmaf(xv[k], w1b[k].z, h1.z);
    h1.w = fmaf(xv[k], w1b[k].w, h1.w);
  }
  float pa = 0.f, pb = 0.f;
  pa = fmaf(fmaxf(h0.x, 0.f), w2a.x, pa);
  pa = fmaf(fmaxf(h0.y, 0.f), w2a.y, pa);
  pa = fmaf(fmaxf(h0.z, 0.f), w2a.z, pa);
  pa = fmaf(fmaxf(h0.w, 0.f), w2a.w, pa);
  pb = fmaf(fmaxf(h1.x, 0.f), w2b.x, pb);
  pb = fmaf(fmaxf(h1.y, 0.f), w2b.y, pb);
  pb = fmaf(fmaxf(h1.z, 0.f), w2b.z, pb);
  pb = fmaf(fmaxf(h1.w, 0.f), w2b.w, pb);
  return dpp_add16(pa + pb);
}

// Named weight register set + loader (software pipeline stage).
struct WSet {
  float4 w1a[8], w1b[8];
  float4 b1a, b1b, w2a, w2b;
  float  b2;
};

__device__ __forceinline__ void loadW(WSet& S, int m0,
                                      const float* __restrict__ W1,
                                      const float* __restrict__ b1,
                                      const float* __restrict__ W2,
                                      const float* __restrict__ b2, int g) {
  const float4* w1p = (const float4*)(W1 + (size_t)m0 * (K_TOP * H_DIM));
#pragma unroll
  for (int k = 0; k < 8; ++k) {
    S.w1a[k] = w1p[k * 32 + 2 * g];
    S.w1b[k] = w1p[k * 32 + 2 * g + 1];
  }
  S.b1a = ((const float4*)(b1 + m0 * H_DIM))[2 * g];
  S.b1b = ((const float4*)(b1 + m0 * H_DIM))[2 * g + 1];
  S.w2a = ((const float4*)(W2 + m0 * H_DIM))[2 * g];
  S.w2b = ((const float4*)(W2 + m0 * H_DIM))[2 * g + 1];
  S.b2  = b2[m0];
}

// ---------------------------------------------------------------------------
// Fused compute, R16 champion + two changes:
//  (1) routing resolution is per-wave wave-uniform (readfirstlane -> scalar
//      loads; no LDS arrays, no tid<128 coupling);
//  (2) slots 0/1's weight sets are loaded into registers BEFORE the barrier,
//      so their L2 latency hides under the x-DMA drain; slots 2/3 prefetched
//      2-deep during compute (A/B named sets, static indexing).
__global__ __launch_bounds__(256, 2)
void fused_compute(const float* __restrict__ x,
                   const float* __restrict__ W1_0, const float* __restrict__ b1_0,
                   const float* __restrict__ W2_0, const float* __restrict__ b2_0,
                   const float* __restrict__ W1_1, const float* __restrict__ b1_1,
                   const float* __restrict__ W2_1, const float* __restrict__ b2_1,
                   const int* __restrict__ ws, float* __restrict__ out) {
  __shared__ __align__(16) float xt[ROWS * XP];   // 33.3 KB x-tile
  __shared__ float tile[16 * 18];                 // layer-0 outputs [slot][row]

  const int tid  = threadIdx.x;
  const int lane = tid & 63;
  const int uwid = __builtin_amdgcn_readfirstlane(tid >> 6);  // wave id, SGPR
  const int rowbase = blockIdx.x * ROWS;

  // ---- stage x-tile via direct HBM->LDS DMA (no VGPR staging) ----
#pragma unroll
  for (int i = 0; i < 8; ++i) {
    const int chunk = uwid * 8 + i;     // wave-uniform, 0..31
    const int row   = chunk >> 1;
    const int half  = chunk & 1;
    const float* gsrc = x + (size_t)(rowbase + row) * D_IN + half * 256 +
                        lane * 4;
    float* ldst = xt + row * XP + half * 256;   // wave-uniform base
    __builtin_amdgcn_global_load_lds(
        (const __attribute__((address_space(1))) void*)gsrc,
        (__attribute__((address_space(3))) void*)ldst, 16, 0, 0);
  }

  // ---- per-wave uniform routing resolution (scalar chain, under the DMA) --
  const int m1A = ws[0];
  const int m1B = ws[1];
  int m0s[4];
  int cols[4][8];
#pragma unroll
  for (int si = 0; si < 4; ++si) {
    const int s  = uwid * 4 + si;
    const int m1 = (s < 8) ? m1A : m1B;
    m0s[si] = ws[64 + m1 * 8 + (s & 7)];
#pragma unroll
    for (int k = 0; k < 8; ++k) cols[si][k] = ws[2048 + m0s[si] * 8 + k];
  }

  const int g  = lane & 15;             // h-group: units 8g..8g+7
  const int rq = lane >> 4;             // row-in-group 0..3

  // ---- preload slots 0/1 weights BEFORE the barrier (hide under DMA) ----
  WSet A, B;
  loadW(A, m0s[0], W1_0, b1_0, W2_0, b2_0, g);
  loadW(B, m0s[1], W1_0, b1_0, W2_0, b2_0, g);

  __syncthreads();                      // drains DMA + in-flight weight loads

  // ---- layer 0: wave w -> slots 4w..4w+3, A/B 2-deep pipeline ----
#pragma unroll
  for (int si = 0; si < 4; ++si) {
    const WSet& S = (si & 1) ? B : A;
    const int sg = uwid * 4 + si;       // global slot for tile row
    int cv[8];
#pragma unroll
    for (int k = 0; k < 8; ++k) cv[k] = cols[si][k];

#pragma unroll
    for (int it = 0; it < 4; ++it) {
      const int r = it * 4 + rq;
      const float* xrow = xt + r * XP;
      float xv[8];
#pragma unroll
      for (int k = 0; k < 8; ++k) xv[k] = xrow[cv[k]];
      const float p = slice8(S.w1a, S.w1b, S.b1a, S.b1b, S.w2a, S.w2b, xv);
      if (g == 0) tile[sg * 18 + r] = p + S.b2;
    }
    // prefetch slot si+2 into the set just consumed
    if (si == 0) loadW(A, m0s[2], W1_0, b1_0, W2_0, b2_0, g);
    if (si == 1) loadW(B, m0s[3], W1_0, b1_0, W2_0, b2_0, g);
  }
  __syncthreads();

  // ---- layer 1: wave w -> module j=w&1, row-half w>>1; + sigmoid ----
  {
    const int j  = uwid & 1;
    const int rh = uwid >> 1;
    const int m1 = j ? m1B : m1A;
    WSet L;
    loadW(L, m1, W1_1, b1_1, W2_1, b2_1, g);

#pragma unroll
    for (int it = 0; it < 2; ++it) {
      const int r = rh * 8 + it * 4 + rq;
      float xv[8];
#pragma unroll
      for (int k = 0; k < 8; ++k) xv[k] = tile[(j * 8 + k) * 18 + r];
      const float p = slice8(L.w1a, L.w1b, L.b1a, L.b1b, L.w2a, L.w2b, xv);
      if (g == 0) {
        const float v = p + L.b2;
        out[(size_t)(rowbase + r) * 2 + j] = 1.f / (1.f + __expf(-v));
      }
    }
  }
}

// ---------------------------------------------------------------------------
extern "C" void kernel_launch(void* const* d_in, const int* in_sizes, int n_in,
                              void* d_out, int out_size, void* d_ws, size_t ws_size,
                              hipStream_t stream) {
  const float* x       = (const float*)d_in[0];
  const int*   task_id = (const int*)  d_in[1];
  const float* emb0    = (const float*)d_in[2];
  const float* emb1    = (const float*)d_in[3];
  const float* emb_out = (const float*)d_in[4];
  const float* W1_0    = (const float*)d_in[5];
  const float* b1_0    = (const float*)d_in[6];
  const float* W2_0    = (const float*)d_in[7];
  const float* b2_0    = (const float*)d_in[8];
  const float* W1_1    = (const float*)d_in[9];
  const float* b1_1    = (const float*)d_in[10];
  const float* W2_1    = (const float*)d_in[11];
  const float* b2_1    = (const float*)d_in[12];

  int* ws = (int*)d_ws;

  route_pre<<<dim3(32, 2), 256, 0, stream>>>(task_id, emb0, emb1, emb_out, ws);
  fused_compute<<<B_SZ / ROWS, 256, 0, stream>>>(x, W1_0, b1_0, W2_0, b2_0,
                                                 W1_1, b1_1, W2_1, b2_1,
                                                 ws, (float*)d_out);
}